// Round 1
// baseline (1180.799 us; speedup 1.0000x reference)
//
#include <hip/hip_runtime.h>
#include <cstdint>
#include <cstddef>

// ---------------------------------------------------------------------------
// JointRetriveDeformHead — fp32 reference-accurate implementation (round 1)
// B=64, P=1024 pts, D=256, S=1024 sources, K=10, NPART=16, PL=32, NPAR=96,
// PSRC=512.
// ---------------------------------------------------------------------------

#define NB    64
#define NPTS  1024
#define NSRC  1024
#define DIM   256
#define KRET  10
#define NPART 16
#define PL    32
#define NPAR  96
#define P3    1536   // 3*PSRC

// ============================ PointNet (fused) =============================
// grid (16 chunks, 64 batch, 2 encoders), 256 threads.
// chunk = 64 points. layer1 -> h1 LDS -> layer2 -> h2 LDS -> layer3 + maxpool
// -> atomicMax into g[e][b][256].
__global__ __launch_bounds__(256) void pointnet_kernel(
    const float* __restrict__ noc,
    const float* __restrict__ te_W1, const float* __restrict__ te_b1,
    const float* __restrict__ te_W2, const float* __restrict__ te_b2,
    const float* __restrict__ te_W3, const float* __restrict__ te_b3,
    const float* __restrict__ re_W1, const float* __restrict__ re_b1,
    const float* __restrict__ re_W2, const float* __restrict__ re_b2,
    const float* __restrict__ re_W3, const float* __restrict__ re_b3,
    float* __restrict__ g)
{
  const int chunk = blockIdx.x;   // 0..15
  const int b     = blockIdx.y;   // 0..63
  const int e     = blockIdx.z;   // 0: te, 1: re

  const float* W1 = e ? re_W1 : te_W1;  const float* b1 = e ? re_b1 : te_b1;
  const float* W2 = e ? re_W2 : te_W2;  const float* b2 = e ? re_b2 : te_b2;
  const float* W3 = e ? re_W3 : te_W3;  const float* b3 = e ? re_b3 : te_b3;

  __shared__ __align__(16) float h1L[64][72];    // [point][64 dims + pad]
  __shared__ __align__(16) float h2L[64][132];   // [point][128 dims + pad]

  const int t = threadIdx.x;

  // ---- Phase A: layer1 (K=3 -> 64) ----
  {
    const int p = t & 63;
    const int w = t >> 6;           // wave id -> k group
    const float p0 = noc[(b*3 + 0)*NPTS + chunk*64 + p];
    const float p1 = noc[(b*3 + 1)*NPTS + chunk*64 + p];
    const float p2 = noc[(b*3 + 2)*NPTS + chunk*64 + p];
    #pragma unroll
    for (int kk = 0; kk < 16; ++kk) {
      const int k = w*16 + kk;
      float v = b1[k] + p0*W1[0*64 + k] + p1*W1[1*64 + k] + p2*W1[2*64 + k];
      h1L[p][k] = fmaxf(v, 0.f);
    }
  }
  __syncthreads();

  // ---- Phase B: layer2 (64x128, K=64), micro-tile 8p x 4j ----
  {
    const int tp = t >> 5;   // 0..7
    const int tj = t & 31;   // 0..31
    float acc[8][4];
    #pragma unroll
    for (int pp = 0; pp < 8; ++pp)
      #pragma unroll
      for (int jj = 0; jj < 4; ++jj) acc[pp][jj] = 0.f;

    for (int k = 0; k < 64; k += 4) {
      float4 a[8];
      #pragma unroll
      for (int pp = 0; pp < 8; ++pp)
        a[pp] = *(const float4*)&h1L[tp*8 + pp][k];
      float4 w[4];
      #pragma unroll
      for (int kk = 0; kk < 4; ++kk)
        w[kk] = *(const float4*)&W2[(k + kk)*128 + tj*4];
      #pragma unroll
      for (int pp = 0; pp < 8; ++pp) {
        const float* av = (const float*)&a[pp];
        #pragma unroll
        for (int kk = 0; kk < 4; ++kk) {
          const float* wv = (const float*)&w[kk];
          #pragma unroll
          for (int jj = 0; jj < 4; ++jj)
            acc[pp][jj] += av[kk] * wv[jj];
        }
      }
    }
    float4 bv = *(const float4*)&b2[tj*4];
    const float* bvv = (const float*)&bv;
    #pragma unroll
    for (int pp = 0; pp < 8; ++pp) {
      float4 r;
      float* rv = (float*)&r;
      #pragma unroll
      for (int jj = 0; jj < 4; ++jj)
        rv[jj] = fmaxf(acc[pp][jj] + bvv[jj], 0.f);
      *(float4*)&h2L[tp*8 + pp][tj*4] = r;
    }
  }
  __syncthreads();

  // ---- Phase C: layer3 (64x256, K=128) + maxpool, micro-tile 8p x 8j ----
  {
    const int tp = t >> 5;   // 0..7 -> points 8tp..
    const int tj = t & 31;   // 0..31 -> j 8tj..
    float acc[8][8];
    #pragma unroll
    for (int pp = 0; pp < 8; ++pp)
      #pragma unroll
      for (int jj = 0; jj < 8; ++jj) acc[pp][jj] = 0.f;

    for (int k = 0; k < 128; k += 4) {
      float4 a[8];
      #pragma unroll
      for (int pp = 0; pp < 8; ++pp)
        a[pp] = *(const float4*)&h2L[tp*8 + pp][k];
      float4 w0[4], w1[4];
      #pragma unroll
      for (int kk = 0; kk < 4; ++kk) {
        w0[kk] = *(const float4*)&W3[(k + kk)*256 + tj*8];
        w1[kk] = *(const float4*)&W3[(k + kk)*256 + tj*8 + 4];
      }
      #pragma unroll
      for (int pp = 0; pp < 8; ++pp) {
        const float* av = (const float*)&a[pp];
        #pragma unroll
        for (int kk = 0; kk < 4; ++kk) {
          const float* wa = (const float*)&w0[kk];
          const float* wb = (const float*)&w1[kk];
          #pragma unroll
          for (int jj = 0; jj < 4; ++jj) {
            acc[pp][jj]     += av[kk] * wa[jj];
            acc[pp][jj + 4] += av[kk] * wb[jj];
          }
        }
      }
    }

    // bias + relu + max over the 8 points of this thread
    float bb[8];
    {
      float4 b3a = *(const float4*)&b3[tj*8];
      float4 b3b = *(const float4*)&b3[tj*8 + 4];
      const float* xa = (const float*)&b3a;
      const float* xb = (const float*)&b3b;
      #pragma unroll
      for (int jj = 0; jj < 4; ++jj) { bb[jj] = xa[jj]; bb[jj+4] = xb[jj]; }
    }
    float m[8];
    #pragma unroll
    for (int jj = 0; jj < 8; ++jj) {
      float mx = 0.f;
      #pragma unroll
      for (int pp = 0; pp < 8; ++pp)
        mx = fmaxf(mx, fmaxf(acc[pp][jj] + bb[jj], 0.f));
      m[jj] = mx;
    }

    // cross-thread max: redL[8 tp][256 j] reuses h1L storage (safe: h1L dead
    // after phase-B barrier, nothing reads it in phase C).
    float* redL = &h1L[0][0];
    {
      float4 r0, r1;
      float* a0 = (float*)&r0; float* a1 = (float*)&r1;
      #pragma unroll
      for (int jj = 0; jj < 4; ++jj) { a0[jj] = m[jj]; a1[jj] = m[jj+4]; }
      *(float4*)&redL[tp*260 + tj*8]     = r0;
      *(float4*)&redL[tp*260 + tj*8 + 4] = r1;
    }
    __syncthreads();
    {
      float mx = redL[t];
      #pragma unroll
      for (int q = 1; q < 8; ++q) mx = fmaxf(mx, redL[q*260 + t]);
      atomicMax((int*)&g[(e*NB + b)*DIM + t], __float_as_int(mx));
    }
  }
}

// ============================ final FC =====================================
// enc[e][b][j] = bf[j] + sum_i g[e][b][i] * Wf[i][j].  grid 128, block 256.
__global__ __launch_bounds__(256) void fc_kernel(
    const float* __restrict__ g,
    const float* __restrict__ te_Wf, const float* __restrict__ te_bf,
    const float* __restrict__ re_Wf, const float* __restrict__ re_bf,
    float* __restrict__ enc)
{
  const int be = blockIdx.x;
  const int e = be >> 6, b = be & 63;
  const float* Wf = e ? re_Wf : te_Wf;
  const float* bf = e ? re_bf : te_bf;
  __shared__ __align__(16) float gL[256];
  const int t = threadIdx.x;
  gL[t] = g[(e*NB + b)*DIM + t];
  __syncthreads();
  float acc = bf[t];
  #pragma unroll 4
  for (int i = 0; i < 256; ++i)
    acc += gL[i] * Wf[i*256 + t];
  enc[(e*NB + b)*DIM + t] = acc;
}

// ===================== distances + top-K (per batch) =======================
__global__ __launch_bounds__(256) void topk_kernel(
    const float* __restrict__ enc,          // [2][64][256]; re at e=1
    const float* __restrict__ var,          // src_variances [S][256]
    const float* __restrict__ codes,        // ret_src_codes [S][256]
    int* __restrict__ idxW)                 // [64][10]
{
  const int b = blockIdx.x;
  const int t = threadIdx.x;
  __shared__ __align__(16) float retL[256];
  __shared__ __align__(16) float dL[1024];
  __shared__ float rV[256];
  __shared__ int   rI[256];

  retL[t] = enc[(1*NB + b)*DIM + t];
  __syncthreads();

  for (int s0 = 0; s0 < 4; ++s0) {
    const int s = s0*256 + t;
    const float4* vp = (const float4*)&var[s*DIM];
    const float4* cp = (const float4*)&codes[s*DIM];
    float acc = 0.f;
    #pragma unroll 4
    for (int c = 0; c < 64; ++c) {
      float4 v  = vp[c];
      float4 cd = cp[c];
      float4 r  = *(const float4*)&retL[c*4];
      float d0 = r.x - cd.x, d1 = r.y - cd.y, d2 = r.z - cd.z, d3 = r.w - cd.w;
      acc += v.x*d0*d0 + v.y*d1*d1 + v.z*d2*d2 + v.w*d3*d3;
    }
    dL[s] = acc;
  }
  __syncthreads();

  for (int kk = 0; kk < KRET; ++kk) {
    float bv = dL[t]; int bi = t;
    #pragma unroll
    for (int s0 = 1; s0 < 4; ++s0) {
      const int s = s0*256 + t;
      const float v = dL[s];
      if (v < bv) { bv = v; bi = s; }
    }
    rV[t] = bv; rI[t] = bi;
    __syncthreads();
    for (int off = 128; off > 0; off >>= 1) {
      if (t < off) {
        const float v = rV[t + off]; const int i2 = rI[t + off];
        if (v < rV[t] || (v == rV[t] && i2 < rI[t])) { rV[t] = v; rI[t] = i2; }
      }
      __syncthreads();
    }
    if (t == 0) { idxW[b*KRET + kk] = rI[0]; dL[rI[0]] = 3.4e38f; }
    __syncthreads();
  }
}

// ============================ decoder (fused) ==============================
// one block per (b,k). 640 blocks, 256 threads.
__global__ __launch_bounds__(256) void decoder_kernel(
    const float* __restrict__ enc,          // te at e=0
    const int*   __restrict__ idxW,
    const float* __restrict__ src_codes,    // [S][256]
    const float* __restrict__ part_latent,  // [S][16][32]
    const float* __restrict__ dW1, const float* __restrict__ db1,  // [544][256]
    const float* __restrict__ dW2, const float* __restrict__ db2,  // [256][256]
    const float* __restrict__ dW3, const float* __restrict__ db3,  // [256][6]
    const float* __restrict__ def_param,    // [S][96]
    const float* __restrict__ proj,         // [S][96][96]
    const float* __restrict__ mat,          // [S][1536][96]
    float* __restrict__ out)                // [64][10][1536]
{
  const int bid = blockIdx.x;
  const int b = bid / KRET, k = bid % KRET;
  const int t = threadIdx.x;

  __shared__ __align__(16) float shx[512];            // [tgt(256) | src(256)]
  __shared__ __align__(16) float partsL[NPART*PL];    // [16][32]
  __shared__ __align__(16) float h1L[NPART][260];
  __shared__ __align__(16) float h2L[NPART][260];
  __shared__ __align__(16) float rawL[NPAR];
  __shared__ __align__(16) float paramsL[NPAR];

  const int s = idxW[b*KRET + k];

  shx[t]        = enc[b*DIM + t];                 // tgt (te encoder)
  shx[256 + t]  = src_codes[s*DIM + t];
  partsL[t]       = part_latent[s*512 + t];
  partsL[256 + t] = part_latent[s*512 + 256 + t];
  __syncthreads();

  // ---- layer1: shared 512-dim part once, + per-part 32-dim tail ----
  {
    float acc = 0.f;
    for (int i4 = 0; i4 < 128; ++i4) {
      float4 xv = *(const float4*)&shx[i4*4];
      acc += xv.x * dW1[(i4*4 + 0)*256 + t];
      acc += xv.y * dW1[(i4*4 + 1)*256 + t];
      acc += xv.z * dW1[(i4*4 + 2)*256 + t];
      acc += xv.w * dW1[(i4*4 + 3)*256 + t];
    }
    float wreg[32];
    #pragma unroll
    for (int i = 0; i < 32; ++i) wreg[i] = dW1[(512 + i)*256 + t];
    const float base = acc + db1[t];
    #pragma unroll
    for (int n = 0; n < NPART; ++n) {
      float v = base;
      #pragma unroll
      for (int i = 0; i < 32; ++i)
        v += partsL[n*32 + i] * wreg[i];
      h1L[n][t] = fmaxf(v, 0.f);
    }
  }
  __syncthreads();

  // ---- layer2: 16x256 @ 256x256.  thread (n = t>>4, jt = t&15), acc[16] ----
  {
    const int n  = t >> 4;
    const int jt = t & 15;
    float acc[16];
    #pragma unroll
    for (int jj = 0; jj < 16; ++jj) acc[jj] = 0.f;
    for (int c = 0; c < 256; ++c) {
      const float hv = h1L[n][c];
      const float4* wr = (const float4*)&dW2[c*256 + jt*16];
      const float4 w0 = wr[0], w1 = wr[1], w2 = wr[2], w3 = wr[3];
      acc[0]  += hv*w0.x; acc[1]  += hv*w0.y; acc[2]  += hv*w0.z; acc[3]  += hv*w0.w;
      acc[4]  += hv*w1.x; acc[5]  += hv*w1.y; acc[6]  += hv*w1.z; acc[7]  += hv*w1.w;
      acc[8]  += hv*w2.x; acc[9]  += hv*w2.y; acc[10] += hv*w2.z; acc[11] += hv*w2.w;
      acc[12] += hv*w3.x; acc[13] += hv*w3.y; acc[14] += hv*w3.z; acc[15] += hv*w3.w;
    }
    #pragma unroll
    for (int q = 0; q < 4; ++q) {
      float4 r;
      float* rv = (float*)&r;
      #pragma unroll
      for (int u = 0; u < 4; ++u) {
        const int j = jt*16 + q*4 + u;
        rv[u] = fmaxf(acc[q*4 + u] + db2[j], 0.f);
      }
      *(float4*)&h2L[n][jt*16 + q*4] = r;
    }
  }
  __syncthreads();

  // ---- layer3: 16x256 @ 256x6 -> raw[96] (no relu) ----
  if (t < 96) {
    const int n = t / 6, r = t % 6;
    float acc = db3[r];
    #pragma unroll 4
    for (int c = 0; c < 256; ++c)
      acc += h2L[n][c] * dW3[c*6 + r];
    rawL[t] = acc;   // t == n*6 + r
  }
  __syncthreads();

  // ---- params = proj[s] @ raw + def_param[s] ----
  if (t < NPAR) {
    float acc = def_param[s*NPAR + t];
    const float4* pr = (const float4*)&proj[((size_t)s*NPAR + t)*NPAR];
    #pragma unroll
    for (int j4 = 0; j4 < 24; ++j4) {
      float4 p = pr[j4];
      float4 r = *(const float4*)&rawL[j4*4];
      acc += p.x*r.x + p.y*r.y + p.z*r.z + p.w*r.w;
    }
    paramsL[t] = acc;
  }
  __syncthreads();

  // ---- pts_def = mat[s] @ params  (memory-bound gather) ----
  for (int p = t; p < P3; p += 256) {
    const float4* mr = (const float4*)&mat[(size_t)s*P3*NPAR + (size_t)p*NPAR];
    float acc = 0.f;
    #pragma unroll
    for (int j4 = 0; j4 < 24; ++j4) {
      float4 m = mr[j4];
      float4 pa = *(const float4*)&paramsL[j4*4];
      acc += m.x*pa.x + m.y*pa.y + m.z*pa.z + m.w*pa.w;
    }
    out[((size_t)(b*KRET + k))*P3 + p] = acc;
  }
}

// ============================ launch =======================================
extern "C" void kernel_launch(void* const* d_in, const int* in_sizes, int n_in,
                              void* d_out, int out_size, void* d_ws, size_t ws_size,
                              hipStream_t stream) {
  const float* noc   = (const float*)d_in[0];
  const float* te_W1 = (const float*)d_in[1];
  const float* te_b1 = (const float*)d_in[2];
  const float* te_W2 = (const float*)d_in[3];
  const float* te_b2 = (const float*)d_in[4];
  const float* te_W3 = (const float*)d_in[5];
  const float* te_b3 = (const float*)d_in[6];
  const float* te_Wf = (const float*)d_in[7];
  const float* te_bf = (const float*)d_in[8];
  const float* re_W1 = (const float*)d_in[9];
  const float* re_b1 = (const float*)d_in[10];
  const float* re_W2 = (const float*)d_in[11];
  const float* re_b2 = (const float*)d_in[12];
  const float* re_W3 = (const float*)d_in[13];
  const float* re_b3 = (const float*)d_in[14];
  const float* re_Wf = (const float*)d_in[15];
  const float* re_bf = (const float*)d_in[16];
  const float* dec_W1 = (const float*)d_in[17];
  const float* dec_b1 = (const float*)d_in[18];
  const float* dec_W2 = (const float*)d_in[19];
  const float* dec_b2 = (const float*)d_in[20];
  const float* dec_W3 = (const float*)d_in[21];
  const float* dec_b3 = (const float*)d_in[22];
  const float* ret_src_codes = (const float*)d_in[23];
  const float* src_codes     = (const float*)d_in[24];
  const float* src_variances = (const float*)d_in[25];
  const float* part_latent   = (const float*)d_in[26];
  const float* def_param     = (const float*)d_in[27];
  const float* proj_mat      = (const float*)d_in[28];
  const float* mat           = (const float*)d_in[29];

  float* g    = (float*)d_ws;                 // [2][64][256]
  float* enc  = g + 2*NB*DIM;                 // [2][64][256]
  int*   idxW = (int*)(enc + 2*NB*DIM);       // [64][10]

  hipMemsetAsync(d_ws, 0, 2*NB*DIM*sizeof(float), stream);  // g = 0 (relu>=0)

  pointnet_kernel<<<dim3(16, NB, 2), 256, 0, stream>>>(
      noc, te_W1, te_b1, te_W2, te_b2, te_W3, te_b3,
      re_W1, re_b1, re_W2, re_b2, re_W3, re_b3, g);

  fc_kernel<<<128, 256, 0, stream>>>(g, te_Wf, te_bf, re_Wf, re_bf, enc);

  topk_kernel<<<NB, 256, 0, stream>>>(enc, src_variances, ret_src_codes, idxW);

  decoder_kernel<<<640, 256, 0, stream>>>(
      enc, idxW, src_codes, part_latent,
      dec_W1, dec_b1, dec_W2, dec_b2, dec_W3, dec_b3,
      def_param, proj_mat, mat, (float*)d_out);
}